// Round 3
// baseline (208.140 us; speedup 1.0000x reference)
//
#include <hip/hip_runtime.h>

typedef short bf16x8_t __attribute__((ext_vector_type(8)));
typedef float f32x4_t __attribute__((ext_vector_type(4)));

__device__ __forceinline__ float bf2f(unsigned short h) {
  union { unsigned int u; float f; } v; v.u = ((unsigned int)h) << 16; return v.f;
}
__device__ __forceinline__ unsigned short f2bf(float f) {
  union { float f; unsigned int u; } v; v.f = f;
  unsigned int u = v.u + 0x7FFFu + ((v.u >> 16) & 1u);
  return (unsigned short)(u >> 16);
}

// Static device workspace (no d_ws dependence).
__device__ __align__(16) unsigned short g_hT[16 * 1024 * 256];     // GN out [b][n][c]; reused as attn OT
__device__ __align__(16) unsigned short g_qT[16 * 4 * 1024 * 64];  // [b][h][n][d]
__device__ __align__(16) unsigned short g_kT[16 * 4 * 1024 * 64];  // [b][h][n][d]
__device__ __align__(16) unsigned short g_vN[16 * 4 * 64 * 1024];  // [b][h][d][n]
__device__ int g_mode;  // 1 = inputs are bf16, 0 = inputs are f32

// ---------------------------------------------------------------------------
// Dtype detector: for bf16 data, bits 14:7 of each 16-bit half are an exponent
// near 127 (N(0,1) values) -> predicate true ~100%. For f32 data the low half
// of each word is mantissa bits -> ~14%. Majority vote over 256 words.
// ---------------------------------------------------------------------------
__global__ void detect_kernel(const unsigned int* __restrict__ x) {
  int cnt = 0;
#pragma unroll
  for (int i = 0; i < 4; ++i) {
    unsigned int w = x[threadIdx.x * 4 + i];
    unsigned int e = (w >> 7) & 0xFFu;
    cnt += (e >= 100u && e <= 135u) ? 1 : 0;
  }
#pragma unroll
  for (int m = 32; m; m >>= 1) cnt += __shfl_xor(cnt, m, 64);
  if (threadIdx.x == 0) g_mode = (cnt > 128) ? 1 : 0;
}

// Load 8 consecutive elements (8-elem chunk index i8) as packed bf16x8.
__device__ __forceinline__ uint4 ld8(const void* p, int i8, int mode) {
  if (mode) return ((const uint4*)p)[i8];
  float4 a = ((const float4*)p)[2 * i8];
  float4 b = ((const float4*)p)[2 * i8 + 1];
  union { unsigned short u[8]; uint4 v; } r;
  r.u[0] = f2bf(a.x); r.u[1] = f2bf(a.y); r.u[2] = f2bf(a.z); r.u[3] = f2bf(a.w);
  r.u[4] = f2bf(b.x); r.u[5] = f2bf(b.y); r.u[6] = f2bf(b.z); r.u[7] = f2bf(b.w);
  return r.v;
}
__device__ __forceinline__ float ld1(const void* p, int i, int mode) {
  return mode ? bf2f(((const unsigned short*)p)[i]) : ((const float*)p)[i];
}

// ---------------------------------------------------------------------------
// Kernel 1: GroupNorm.  x[b][c][n] -> g_hT[b][n][c] (bf16, transposed)
// One block per (b, g): 8 channels x 1024 spatial = 8192 elems, 32/thread.
// ---------------------------------------------------------------------------
__global__ __launch_bounds__(256) void gn_kernel(
    const void* __restrict__ xin, const void* __restrict__ gamma,
    const void* __restrict__ beta) {
  const int mode = g_mode;
  const int b = blockIdx.x >> 5, g = blockIdx.x & 31;
  const int t = threadIdx.x;
  const size_t base = (size_t)(b * 256 + g * 8) * 1024;

  __shared__ __align__(16) unsigned short lds[8192];
  __shared__ float red[16];

  float vals[32];
  float s = 0.f, sq = 0.f;
  if (mode) {
    const uint4* xg = (const uint4*)((const unsigned short*)xin + base);
#pragma unroll
    for (int p = 0; p < 4; ++p) {
      uint4 raw = xg[t + p * 256];
      const unsigned short* pr = (const unsigned short*)&raw;
#pragma unroll
      for (int j = 0; j < 8; ++j) {
        float f = bf2f(pr[j]);
        vals[p * 8 + j] = f;
        s += f; sq += f * f;
      }
    }
  } else {
    const float4* xg = (const float4*)((const float*)xin + base);
#pragma unroll
    for (int p = 0; p < 4; ++p) {
      int idx = t + p * 256;
      float4 a = xg[2 * idx], c = xg[2 * idx + 1];
      float tmp[8] = {a.x, a.y, a.z, a.w, c.x, c.y, c.z, c.w};
#pragma unroll
      for (int j = 0; j < 8; ++j) {
        vals[p * 8 + j] = tmp[j];
        s += tmp[j]; sq += tmp[j] * tmp[j];
      }
    }
  }
#pragma unroll
  for (int m = 32; m; m >>= 1) {
    s += __shfl_xor(s, m, 64);
    sq += __shfl_xor(sq, m, 64);
  }
  const int w = t >> 6;
  if ((t & 63) == 0) { red[w] = s; red[8 + w] = sq; }
  __syncthreads();
  s = red[0] + red[1] + red[2] + red[3];
  sq = red[8] + red[9] + red[10] + red[11];
  const float mu = s * (1.f / 8192.f);
  const float var = sq * (1.f / 8192.f) - mu * mu;
  const float rstd = rsqrtf(var + 1e-5f);

#pragma unroll
  for (int p = 0; p < 4; ++p) {
    int idx = t + p * 256;
    int c = idx >> 7;  // chunk of 8 elems -> channel = (idx*8)/1024
    float ga = ld1(gamma, g * 8 + c, mode) * rstd;
    float be = ld1(beta, g * 8 + c, mode) - mu * ga;
    union { unsigned short u[8]; uint4 v; } pk;
#pragma unroll
    for (int j = 0; j < 8; ++j) pk.u[j] = f2bf(vals[p * 8 + j] * ga + be);
    ((uint4*)lds)[idx] = pk.v;
  }
  __syncthreads();

  unsigned short* dstbase = g_hT + (size_t)b * 1024 * 256 + g * 8;
#pragma unroll
  for (int p = 0; p < 4; ++p) {
    int n = t + p * 256;
    union { unsigned short u[8]; uint4 v; } pk;
#pragma unroll
    for (int c = 0; c < 8; ++c) pk.u[c] = lds[c * 1024 + n];
    *(uint4*)(dstbase + (size_t)n * 256) = pk.v;
  }
}

// ---------------------------------------------------------------------------
// Kernel 2: channel GEMM  C[o][n] = sum_k W[o][k] * hT[n][k]  (K = 256)
// MODE 0: qkv -> q,k transposed [b][h][n][d], v natural [b][h][d][n], +bias
//         (row o = head*192 + type*64 + d : head = oty/3, type = oty%3)
// MODE 1: proj -> out[b][c][n] = C + bias + residual x
// ---------------------------------------------------------------------------
template <int MODE>
__global__ __launch_bounds__(256) void gemm_ct(
    const void* __restrict__ W, const void* __restrict__ bias,
    const void* __restrict__ xres, void* __restrict__ outp) {
  const int mode = g_mode;
  const int n0 = blockIdx.x * 64;
  const int oty = blockIdx.y;
  const int o0 = oty * 64;
  const int b = blockIdx.z;
  const int t = threadIdx.x;
  const int mrow = t >> 2, kq = t & 3;
  const int w = t >> 6, lane = t & 63, quad = lane >> 4, l15 = lane & 15;

  __shared__ uint4 as[256];
  __shared__ uint4 bs[256];

  const uint4* Bv = (const uint4*)g_hT;
  const int wa = (o0 + mrow) * 32 + kq;            // K=256 -> 32 chunks of 8
  const int wb = (b * 1024 + n0 + mrow) * 32 + kq;

  f32x4_t acc[4];
#pragma unroll
  for (int i = 0; i < 4; ++i) acc[i] = (f32x4_t){0.f, 0.f, 0.f, 0.f};

  for (int kb = 0; kb < 32; kb += 4) {
    as[kq * 64 + mrow] = ld8(W, wa + kb, mode);
    bs[kq * 64 + mrow] = Bv[wb + kb];
    __syncthreads();
    bf16x8_t af = __builtin_bit_cast(bf16x8_t, as[quad * 64 + w * 16 + l15]);
#pragma unroll
    for (int ns = 0; ns < 4; ++ns) {
      bf16x8_t bf = __builtin_bit_cast(bf16x8_t, bs[quad * 64 + ns * 16 + l15]);
      acc[ns] = __builtin_amdgcn_mfma_f32_16x16x32_bf16(af, bf, acc[ns], 0, 0, 0);
    }
    __syncthreads();
  }

  const int r0 = w * 16 + quad * 4;
  float bi[4];
#pragma unroll
  for (int r = 0; r < 4; ++r) bi[r] = ld1(bias, o0 + r0 + r, mode);

  if (MODE == 0) {
    const int head = oty / 3, type = oty % 3;
    if (type < 2) {
      unsigned short* dst = (type == 0 ? g_qT : g_kT) + (size_t)(b * 4 + head) * 65536;
#pragma unroll
      for (int ns = 0; ns < 4; ++ns) {
        int n = n0 + ns * 16 + l15;
        ushort4 pk;
        pk.x = f2bf(acc[ns][0] + bi[0]);
        pk.y = f2bf(acc[ns][1] + bi[1]);
        pk.z = f2bf(acc[ns][2] + bi[2]);
        pk.w = f2bf(acc[ns][3] + bi[3]);
        *(ushort4*)(dst + (size_t)n * 64 + r0) = pk;
      }
    } else {
      unsigned short* dst = g_vN + (size_t)(b * 4 + head) * 65536;
#pragma unroll
      for (int ns = 0; ns < 4; ++ns) {
        int n = n0 + ns * 16 + l15;
#pragma unroll
        for (int r = 0; r < 4; ++r)
          dst[(size_t)(r0 + r) * 1024 + n] = f2bf(acc[ns][r] + bi[r]);
      }
    }
  } else {
#pragma unroll
    for (int ns = 0; ns < 4; ++ns) {
      int n = n0 + ns * 16 + l15;
#pragma unroll
      for (int r = 0; r < 4; ++r) {
        int idx = ((b * 256 + o0 + r0 + r) << 10) + n;
        float v = acc[ns][r] + bi[r] + ld1(xres, idx, mode);
        if (mode) ((unsigned short*)outp)[idx] = f2bf(v);
        else      ((float*)outp)[idx] = v;
      }
    }
  }
}

// ---------------------------------------------------------------------------
// Kernel 3: flash attention.  Per block: (b, head, 64-query tile).
// g_qT,g_kT: [b][h][n][d];  g_vN: [b][h][d][n].
// S = q k^T * 0.125 -> online softmax -> O += P V (P via LDS round trip).
// Output: g_hT reused as OT[b][n][c], c = h*64 + d.
// ---------------------------------------------------------------------------
__global__ __launch_bounds__(256) void attn_kernel() {
  const int n0 = blockIdx.x * 64;
  const int h = blockIdx.y;
  const int b = blockIdx.z;
  const int bh = b * 4 + h;
  const int t = threadIdx.x;
  const int w = t >> 6, lane = t & 63, quad = lane >> 4, l15 = lane & 15;

  const uint4* qv = (const uint4*)(g_qT + (size_t)bh * 65536);
  const uint4* kv = (const uint4*)(g_kT + (size_t)bh * 65536);
  const uint4* vv = (const uint4*)(g_vN + (size_t)bh * 65536);

  __shared__ uint4 qs[512];
  __shared__ uint4 ks[512];
  __shared__ uint4 vs[512];
  __shared__ __align__(16) unsigned short Ps[4 * 16 * 72];  // stride 72 breaks conflicts

  // stage q tile (frag-ready: qs[dchunk*64 + n] = qT[n0+n][dchunk*8 .. +8])
#pragma unroll
  for (int p = 0; p < 2; ++p) {
    int idx = t + p * 256;
    int n = idx >> 3, dc = idx & 7;
    qs[dc * 64 + n] = qv[(n0 + n) * 8 + dc];
  }

  f32x4_t O[4];
  float mst[4], lst[4];
#pragma unroll
  for (int i = 0; i < 4; ++i) {
    O[i] = (f32x4_t){0.f, 0.f, 0.f, 0.f};
    mst[i] = -1e30f;
    lst[i] = 0.f;
  }

#pragma unroll 1
  for (int mt = 0; mt < 16; ++mt) {
    const int m0 = mt * 64;
#pragma unroll
    for (int p = 0; p < 2; ++p) {
      int idx = t + p * 256;
      int r_ = idx >> 3, c_ = idx & 7;
      ks[c_ * 64 + r_] = kv[(m0 + r_) * 8 + c_];
      vs[c_ * 64 + r_] = vv[r_ * 128 + mt * 8 + c_];
    }
    __syncthreads();  // ks/vs staged (covers qs on first iter)

    f32x4_t sacc[4];
#pragma unroll
    for (int i = 0; i < 4; ++i) sacc[i] = (f32x4_t){0.f, 0.f, 0.f, 0.f};
#pragma unroll
    for (int kk = 0; kk < 2; ++kk) {
      bf16x8_t aq = __builtin_bit_cast(bf16x8_t, qs[(kk * 4 + quad) * 64 + w * 16 + l15]);
#pragma unroll
      for (int ms = 0; ms < 4; ++ms) {
        bf16x8_t bk = __builtin_bit_cast(bf16x8_t, ks[(kk * 4 + quad) * 64 + ms * 16 + l15]);
        sacc[ms] = __builtin_amdgcn_mfma_f32_16x16x32_bf16(aq, bk, sacc[ms], 0, 0, 0);
      }
    }
#pragma unroll
    for (int ms = 0; ms < 4; ++ms)
#pragma unroll
      for (int r = 0; r < 4; ++r) sacc[ms][r] *= 0.125f;

    // row max (rows = quad*4 + r; reduce over the quad's 16 lanes)
    float mx[4];
#pragma unroll
    for (int r = 0; r < 4; ++r)
      mx[r] = fmaxf(fmaxf(sacc[0][r], sacc[1][r]), fmaxf(sacc[2][r], sacc[3][r]));
#pragma unroll
    for (int xm = 1; xm < 16; xm <<= 1)
#pragma unroll
      for (int r = 0; r < 4; ++r) mx[r] = fmaxf(mx[r], __shfl_xor(mx[r], xm, 16));

    float al[4], rs[4];
#pragma unroll
    for (int r = 0; r < 4; ++r) {
      float nm = fmaxf(mst[r], mx[r]);
      al[r] = __expf(mst[r] - nm);
      mst[r] = nm;
      rs[r] = 0.f;
    }
    float pv[4][4];
#pragma unroll
    for (int ms = 0; ms < 4; ++ms)
#pragma unroll
      for (int r = 0; r < 4; ++r) {
        float p = __expf(sacc[ms][r] - mst[r]);
        pv[ms][r] = p;
        rs[r] += p;
      }
#pragma unroll
    for (int xm = 1; xm < 16; xm <<= 1)
#pragma unroll
      for (int r = 0; r < 4; ++r) rs[r] += __shfl_xor(rs[r], xm, 16);
#pragma unroll
    for (int r = 0; r < 4; ++r) lst[r] = lst[r] * al[r] + rs[r];
#pragma unroll
    for (int ds = 0; ds < 4; ++ds)
#pragma unroll
      for (int r = 0; r < 4; ++r) O[ds][r] *= al[r];

    // P: C-layout -> LDS (bf16) -> A-layout
    unsigned short* PsW = Ps + w * 1152;
#pragma unroll
    for (int ms = 0; ms < 4; ++ms)
#pragma unroll
      for (int r = 0; r < 4; ++r)
        PsW[(quad * 4 + r) * 72 + ms * 16 + l15] = f2bf(pv[ms][r]);
    __syncthreads();

#pragma unroll
    for (int km = 0; km < 2; ++km) {
      bf16x8_t ap = *(const bf16x8_t*)(PsW + l15 * 72 + km * 32 + quad * 8);
#pragma unroll
      for (int ds = 0; ds < 4; ++ds) {
        bf16x8_t bv = __builtin_bit_cast(bf16x8_t, vs[(km * 4 + quad) * 64 + ds * 16 + l15]);
        O[ds] = __builtin_amdgcn_mfma_f32_16x16x32_bf16(ap, bv, O[ds], 0, 0, 0);
      }
    }
    __syncthreads();  // protect ks/vs before next stage
  }

  float inv[4];
#pragma unroll
  for (int r = 0; r < 4; ++r) inv[r] = 1.f / lst[r];
  unsigned short* dst = g_hT + ((size_t)b * 1024 + n0 + w * 16 + quad * 4) * 256 + h * 64;
#pragma unroll
  for (int ds = 0; ds < 4; ++ds)
#pragma unroll
    for (int r = 0; r < 4; ++r)
      dst[(size_t)r * 256 + ds * 16 + l15] = f2bf(O[ds][r] * inv[r]);
}

// ---------------------------------------------------------------------------
extern "C" void kernel_launch(void* const* d_in, const int* in_sizes, int n_in,
                              void* d_out, int out_size, void* d_ws, size_t ws_size,
                              hipStream_t stream) {
  detect_kernel<<<1, 64, 0, stream>>>((const unsigned int*)d_in[0]);
  gn_kernel<<<512, 256, 0, stream>>>(d_in[0], d_in[1], d_in[2]);
  gemm_ct<0><<<dim3(16, 12, 16), 256, 0, stream>>>(d_in[3], d_in[4], nullptr, nullptr);
  attn_kernel<<<dim3(16, 4, 16), 256, 0, stream>>>();
  gemm_ct<1><<<dim3(16, 4, 16), 256, 0, stream>>>(d_in[5], d_in[6], d_in[0], d_out);
}